// Round 17
// baseline (447.894 us; speedup 1.0000x reference)
//
#include <hip/hip_runtime.h>
#include <hip/hip_fp16.h>

typedef _Float16 f16;
typedef __attribute__((ext_vector_type(2))) _Float16 f16x2;
typedef __attribute__((ext_vector_type(4))) _Float16 f16x4v;
typedef __attribute__((ext_vector_type(8))) _Float16 f16x8;
typedef __attribute__((ext_vector_type(4))) float f32x4;
typedef __attribute__((ext_vector_type(4))) int i32x4;

#define DEV __device__ __forceinline__

static constexpr int S_ = 2048;
static constexpr int D_ = 2048;
static constexpr int H_ = 16;
static constexpr int HD_ = 128;
static constexpr int B_ = 4;
static constexpr int QKV_ST = 6144;  // fused qkv row stride (Q|K|V)

typedef const __attribute__((address_space(1))) void* gptr_t;
typedef __attribute__((address_space(3))) void* lptr_t;

// async global->LDS, 16B per lane. LDS dest must be wave-uniform; HW writes
// dest + lane*16 (m104 semantics). Compiler manages m0.
DEV void gl_lds16(const void* gsrc, void* lds) {
  __builtin_amdgcn_global_load_lds((gptr_t)gsrc, (lptr_t)lds, 16, 0, 0);
}

// f32 pair -> packed f16x2 bits (v_cvt_pkrtz_f16_f32)
DEV int cvt_pk_i32(float a, float b) {
  return __builtin_bit_cast(int, __builtin_amdgcn_cvt_pkrtz(a, b));
}

__global__ __launch_bounds__(256) void cvt_f32_to_f16(const float* __restrict__ in,
                                                      f16* __restrict__ out, long n) {
  long i0 = ((long)blockIdx.x * 256 + threadIdx.x) * 4;
  long stride = (long)gridDim.x * 256 * 4;
  for (long i = i0; i < n; i += stride) {
    float4 v = *(const float4*)(in + i);
    f16x4v o;
    o[0] = (f16)v.x; o[1] = (f16)v.y; o[2] = (f16)v.z; o[3] = (f16)v.w;
    *(f16x4v*)(out + i) = o;
  }
}

// W (2048 x 2048, row-major K x N) -> Wt (N x K) fp16; 4 weights, one launch.
__global__ __launch_bounds__(256) void wtrans4(const float* __restrict__ W0, const float* __restrict__ W1,
                                               const float* __restrict__ W2, const float* __restrict__ W3,
                                               f16* __restrict__ Wt) {
  __shared__ float tile[32][33];
  int wi = blockIdx.y;
  const float* W = wi == 0 ? W0 : wi == 1 ? W1 : wi == 2 ? W2 : W3;
  f16* dst = Wt + (size_t)wi * D_ * D_;
  int bx = blockIdx.x & 63, by = blockIdx.x >> 6;
  int r0 = by << 5, c0 = bx << 5;
  int tx = threadIdx.x & 31, ty = threadIdx.x >> 5;
#pragma unroll
  for (int i = 0; i < 4; i++) {
    int r = ty + i * 8;
    tile[r][tx] = W[(size_t)(r0 + r) * D_ + c0 + tx];
  }
  __syncthreads();
#pragma unroll
  for (int i = 0; i < 4; i++) {
    int r = ty + i * 8;
    dst[(size_t)(c0 + r) * D_ + r0 + tx] = (f16)tile[tx][r];
  }
}

// swizzled LDS fragment read: [128][64] f16 half-tile, full 3-bit XOR
// swizzle (R14: conflicts measured 0): group = (s*4+lg)^(ln&7).
DEV f16x8 lds_frag(const f16* half, int row, int s, int lg) {
  int byte = row * 128 + s * 64 + lg * 16;
  byte ^= (row & 7) << 4;
  return *(const f16x8*)((const char*)half + byte);
}

// C = A(MxK, row stride lda) * Bt(NxK)^T ; C row stride ldc. 256x256 tile,
// BK=64, 8 waves, 512 thr. Multi-subgroup fusion: subgroup = bid/nwg picks
// B/C offsets (QKV GEMMs share A in one grid). ONE-BARRIER K-loop (R15/16).
// V-SUBGROUP EPILOGUE (R16 fusion): wi==2 writes V^T directly in the
// fragment-linear sigma layout attn consumes (deletes vtrans2). The GEMM
// lane mapping matches the sigma exactly: for value V[row][col] at lane
// l=(lg,ln), fragment (mi,ni): sigma lane == l, e = r4 + 4*(mi&1),
// kk = (mi>>1)&1, t = tilebase + (mi>>2), nj = (wn&1)*4 + ni -- so each
// thread's 4 r4-values form one contiguous 8B f16x4 (coalesced 512B/wave).
// VT2 linear space L is EMBEDDED in the V columns of qkv (no extra ws):
// f16 addr = (L>>11)*ldc + (L&2047), relative to C (= qkv+4096 for wi=2).
template <typename CT>
__global__ __launch_bounds__(512, 2) void gemm8(const f16* __restrict__ A, const f16* __restrict__ Bt,
                                                CT* __restrict__ C, int M, int N, int K,
                                                int lda, int ldc, long subB, long subC) {
  __shared__ alignas(16) f16 As[2][2][128 * 64];
  __shared__ alignas(16) f16 Bs[2][2][128 * 64];
  int nbx = N >> 8;
  int nwg = (M >> 8) * nbx;  // per-subgroup wg count (%8==0; ours: 256)
  int bid = blockIdx.x;
  int wi = bid / nwg;                            // subgroup (0 if plain)
  int bidl = bid - wi * nwg;
  Bt += (size_t)wi * subB;
  C += (size_t)wi * subC;
  int wg = (bidl & 7) * (nwg >> 3) + (bidl >> 3);  // XCD-contiguous chunks
  int bx = wg % nbx, by = wg / nbx;
  int tid = threadIdx.x, w = tid >> 6, l = tid & 63;
  int wm = w >> 2, wn = w & 3, lg = l >> 4, ln = l & 15;
  int nt = K >> 6;
  const f16* Ab = A + (size_t)(by * 256) * lda;
  const f16* Bb = Bt + (size_t)(bx * 256) * K;

  // stage one [128][64] half-tile: linear LDS dest (gl_lds16 requirement),
  // source slot = (l&7) ^ (row&7) -- same involution as lds_frag (rule #21).
  auto stageA = [&](const f16* src0, int kt, f16* dst) {
#pragma unroll
    for (int j = 0; j < 2; j++) {
      int c = j * 8 + w;                       // 1KB chunk
      int row = c * 8 + (l >> 3);
      int scol = ((l & 7) ^ (row & 7)) << 3;   // elems (16B units)
      gl_lds16(src0 + (size_t)row * lda + kt * 64 + scol, (char*)dst + c * 1024);
    }
  };
  auto stageB = [&](const f16* src0, int kt, f16* dst) {
#pragma unroll
    for (int j = 0; j < 2; j++) {
      int c = j * 8 + w;                       // 1KB chunk
      int row = c * 8 + (l >> 3);
      int scol = ((l & 7) ^ (row & 7)) << 3;
      gl_lds16(src0 + (size_t)row * K + kt * 64 + scol, (char*)dst + c * 1024);
    }
  };

  f32x4 acc[8][4] = {};

  // prologue: tile0 A+B
  stageA(Ab, 0, As[0][0]);
  stageA(Ab + (size_t)128 * lda, 0, As[0][1]);
  stageB(Bb, 0, Bs[0][0]);
  stageB(Bb + (size_t)128 * K, 0, Bs[0][1]);

  for (int t = 0; t < nt; t++) {
    // tile-entry drain: A(t)+B(t) landed for every wave, collective barrier
    asm volatile("s_waitcnt vmcnt(0)" ::: "memory");
    __builtin_amdgcn_s_barrier();
    asm volatile("" ::: "memory");
    // 1-ahead stage of BOTH operands into the opposite buffers, issued
    // FIRST for maximum in-flight slack (buffers [(t+1)&1] held t-1 data;
    // all reads of them completed before any wave reached this barrier).
    if (t + 1 < nt) {
      stageA(Ab, t + 1, As[(t + 1) & 1][0]);
      stageA(Ab + (size_t)128 * lda, t + 1, As[(t + 1) & 1][1]);
      stageB(Bb, t + 1, Bs[(t + 1) & 1][0]);
      stageB(Bb + (size_t)128 * K, t + 1, Bs[(t + 1) & 1][1]);
    }
    const f16* Ah = As[t & 1][wm];
    const f16* Bh = Bs[t & 1][wn >> 1];
    int br0 = (wn & 1) * 64;
    f16x8 alo[4], ahi[4], b0[4], b1[4];
    // all B fragments (k0,k1) + A k0 (both row-halves)
#pragma unroll
    for (int i = 0; i < 4; i++) b0[i] = lds_frag(Bh, br0 + i * 16 + ln, 0, lg);
#pragma unroll
    for (int i = 0; i < 4; i++) b1[i] = lds_frag(Bh, br0 + i * 16 + ln, 1, lg);
#pragma unroll
    for (int i = 0; i < 4; i++) alo[i] = lds_frag(Ah, i * 16 + ln, 0, lg);
#pragma unroll
    for (int i = 0; i < 4; i++) ahi[i] = lds_frag(Ah, 64 + i * 16 + ln, 0, lg);
    __builtin_amdgcn_s_setprio(1);
#pragma unroll
    for (int mi = 0; mi < 4; mi++)
#pragma unroll
      for (int ni = 0; ni < 4; ni++) {
        acc[mi][ni] = __builtin_amdgcn_mfma_f32_16x16x32_f16(alo[mi], b0[ni], acc[mi][ni], 0, 0, 0);
        acc[mi + 4][ni] = __builtin_amdgcn_mfma_f32_16x16x32_f16(ahi[mi], b0[ni], acc[mi + 4][ni], 0, 0, 0);
      }
    __builtin_amdgcn_s_setprio(0);
    // A k1 fragments from As[t&1]: not overwritten this tile, no barrier
#pragma unroll
    for (int i = 0; i < 4; i++) alo[i] = lds_frag(Ah, i * 16 + ln, 1, lg);
#pragma unroll
    for (int i = 0; i < 4; i++) ahi[i] = lds_frag(Ah, 64 + i * 16 + ln, 1, lg);
    __builtin_amdgcn_s_setprio(1);
#pragma unroll
    for (int mi = 0; mi < 4; mi++)
#pragma unroll
      for (int ni = 0; ni < 4; ni++) {
        acc[mi][ni] = __builtin_amdgcn_mfma_f32_16x16x32_f16(alo[mi], b1[ni], acc[mi][ni], 0, 0, 0);
        acc[mi + 4][ni] = __builtin_amdgcn_mfma_f32_16x16x32_f16(ahi[mi], b1[ni], acc[mi + 4][ni], 0, 0, 0);
      }
    __builtin_amdgcn_s_setprio(0);
    asm volatile("" ::: "memory");
  }

  int row0 = by * 256 + wm * 128;
  int col0 = bx * 256 + wn * 64;
  if constexpr (sizeof(CT) == 2) {
    if (wi == 2) {
      // V^T fragment-linear write (vtrans2 fused away). Lane-local, no shfl.
#pragma unroll
      for (int mi = 0; mi < 8; mi++)
#pragma unroll
        for (int ni = 0; ni < 4; ni++) {
          f16x4v pv;
#pragma unroll
          for (int r4 = 0; r4 < 4; r4++) pv[r4] = (f16)acc[mi][ni][r4];
          int row = row0 + mi * 16 + lg * 4;
          int col = col0 + ni * 16 + ln;
          int bh = ((row >> 11) << 4) + ((col >> 7) & 15);
          int tt = (row & 2047) >> 6;
          int cc = (((col & 127) >> 4) << 1) + ((mi >> 1) & 1);
          long L = ((long)(bh * 32 + tt) << 13) + cc * 512 + l * 8 + 4 * (mi & 1);
          *(f16x4v*)(&C[(size_t)(L >> 11) * ldc + (L & 2047)]) = pv;
        }
      return;
    }
  }
#pragma unroll
  for (int mi = 0; mi < 8; mi++)
#pragma unroll
    for (int ni = 0; ni < 4; ni++)
#pragma unroll
      for (int r4 = 0; r4 < 4; r4++) {
        int row = row0 + mi * 16 + lg * 4 + r4;
        int col = col0 + ni * 16 + ln;
        float o = acc[mi][ni][r4];
        if constexpr (sizeof(CT) == 2) {
          float oo = __shfl_xor(o, 1);
          if (!(ln & 1)) {
            f16x2 pp; pp[0] = (f16)o; pp[1] = (f16)oo;
            *(f16x2*)(&C[(size_t)row * ldc + col]) = pp;
          }
        } else {
          C[(size_t)row * ldc + col] = o;
        }
      }
}

__global__ __launch_bounds__(256) void rope_table(float2* __restrict__ tab, const int* __restrict__ st) {
  int i = blockIdx.x * 256 + threadIdx.x;  // S*64 entries
  int s = i >> 6, j = i & 63;
  float theta = powf(10000.f, -(float)j / 64.f);
  float ang = (float)(s + st[0]) * theta;
  tab[i] = make_float2(cosf(ang), sinf(ang));
}

// RoPE over the K columns (2048..4095) of the fused qkv buffer, in place.
__global__ __launch_bounds__(256) void rope_apply_k(f16* __restrict__ QKV, const float2* __restrict__ tab,
                                                    long npairs) {
  long i0 = (long)blockIdx.x * 256 + threadIdx.x;
  long stride = (long)gridDim.x * 256;
  for (long p = i0; p < npairs; p += stride) {
    long row = p >> 10;            // 1024 K-pairs per row
    int jp = (int)(p & 1023);
    int s = (int)(row & (S_ - 1));
    float2 cs = tab[s * 64 + (jp & 63)];
    f16* px = QKV + row * QKV_ST + 2048 + 2 * jp;
    f16x2 v = *(const f16x2*)px;
    float xe = (float)v[0], xo = (float)v[1];
    float re = xe * cs.x - xo * cs.y;
    float ro = xe * cs.y + xo * cs.x;
    f16x2 o; o[0] = (f16)re; o[1] = (f16)ro;
    *(f16x2*)px = o;
  }
}

// flash attention, causal. 8 waves x 16 q-rows (QBLK=128), KV tile = 64,
// TWO KV-TILES PER BARRIER PERIOD: kls[2][2][64*128] (64KB, 2 blocks/CU).
// R11 config (best measured attn, 127.4us). SWAPPED QK^T; lane-local
// softmax; ZERO-SHUFFLE PV: the V GEMM epilogue wrote V^T fragment-linear
// into the V columns of qkv (linear space L -> row L>>11, col 4096+L&2047),
// so each PV A-fragment is one contiguous 1KB wave load:
// addr = (bh*128 + t*4 + (c>>2)) * 6144 + 4096 + (c&3)*512 + l*8.
// Q-RoPE fused into Q load; V chunks 0-7 after QK^T; UNIFORM blocks via
// causal pairing (15-u, u). O written back into Q columns.
// lsum quad-reduce deferred to epilogue. log2 scores; T13 defer-max THR=8.
__global__ __launch_bounds__(512, 4) void attn(f16* __restrict__ QKV, const float2* __restrict__ tab) {
  __shared__ alignas(16) f16 kls[2][2][64 * 128];
  int id = blockIdx.x;                   // 512 blocks
  int r8 = id & 7, j = id >> 3;          // j: 0..63 per XCD-residue
  int u = j & 7, g = j >> 3;             // u: pair id, g: bh group 0..7
  int bh = r8 + (g << 3);                // 8 bh's per XCD residue, bh-major
  int b = bh >> 4, h = bh & 15;
  int tid = threadIdx.x, w = tid >> 6, l = tid & 63, lg = l >> 4, ln = l & 15;

  const float QSCALE = 0.12751744910173355f;  // log2(e)/sqrt(128)
  const f16* kp = QKV + (size_t)(b * S_) * QKV_ST + 2048 + h * HD_;
  const f16* vb = QKV + 4096;
  int vrow0 = bh * 128;                  // V^T linear rows (2048 f16 each)

  auto stageK = [&](int buf, int half, int kv0) {
#pragma unroll
    for (int jj = 0; jj < 2; jj++) {
      int i = jj * 8 + w;
      int byte = i * 1024 + 16 * l;
      int r = byte >> 8;                       // row 0..63
      int c = (((byte >> 4) & 15) - r) & 15;   // inverse additive swizzle
      gl_lds16(kp + (size_t)(kv0 + r) * QKV_ST + c * 8, (char*)kls[buf][half] + i * 1024);
    }
  };
  auto vload = [&](int t, int c) -> f16x8 {
    return *(const f16x8*)(vb + (size_t)(vrow0 + t * 4 + (c >> 2)) * QKV_ST + (c & 3) * 512 + l * 8);
  };

#pragma unroll 1
  for (int pi = 0; pi < 2; pi++) {
    int qsel = pi ? u : 15 - u;          // heavy pass first (K range in L2)
    int q0 = qsel << 7;
    int qrow = q0 + w * 16 + ln;         // this lane's q row (output column)
    f16* qp = QKV + (size_t)(b * S_ + qrow) * QKV_ST + h * HD_;
    const float2* tq = tab + (size_t)qrow * 64;
    f16x8 qf[4];
#pragma unroll
    for (int kc = 0; kc < 4; kc++) {
      f16x8 q = *(const f16x8*)(qp + kc * 32 + lg * 8);
#pragma unroll
      for (int p = 0; p < 4; p++) {
        float2 cs = tq[kc * 16 + lg * 4 + p];
        float e0 = (float)q[2 * p], e1 = (float)q[2 * p + 1];
        q[2 * p] = (f16)((e0 * cs.x - e1 * cs.y) * QSCALE);
        q[2 * p + 1] = (f16)((e0 * cs.y + e1 * cs.x) * QSCALE);
      }
      qf[kc] = q;
    }

    float m = -1e30f, lsum = 0.f;        // lsum: LANE-LOCAL partial
    f32x4 oacc[8] = {};                  // O^T[d = nj*16 + lg*4 + r4][q = ln]

    int np = qsel + 1;                   // periods; nt64 = 2*qsel+2 tiles
    int nt64 = 2 * qsel + 2;
    if (pi) __syncthreads();             // kls readers from prev pass done
    stageK(0, 0, 0);                     // prologue: period 0 (tiles 0,1)
    stageK(0, 1, 64);
#pragma unroll 1
    for (int p = 0; p < np; p++) {
      __syncthreads();  // drains period-p staging; all waves done with buf
      if (p + 1 < np) {
        stageK((p + 1) & 1, 0, (2 * p + 2) << 6);
        stageK((p + 1) & 1, 1, (2 * p + 3) << 6);
      }
#pragma unroll 1
      for (int ii = 0; ii < 2; ii++) {
        int t = 2 * p + ii;
        int kv0 = t << 6;
        // wave-uniform skip: this wave's rows all precede the tile
        if (kv0 > q0 + w * 16 + 15) continue;
        const f16* kb = kls[p & 1][ii];

        // S^T = K Q^T: sf[ni][r4] = S[kv = kv0 + ni*16 + lg*4 + r4][q = ln]
        f32x4 sf[4];
        __builtin_amdgcn_s_setprio(1);
#pragma unroll
        for (int ni = 0; ni < 4; ni++) {
          int n = ni * 16 + ln;
          f32x4 s = {0.f, 0.f, 0.f, 0.f};
#pragma unroll
          for (int kc = 0; kc < 4; kc++) {
            int mch = kc * 4 + lg;
            f16x8 kf = *(const f16x8*)(&kb[n * 128 + (((mch + n) & 15) << 3)]);
            s = __builtin_amdgcn_mfma_f32_16x16x32_f16(kf, qf[kc], s, 0, 0, 0);
          }
          sf[ni] = s;
        }
        __builtin_amdgcn_s_setprio(0);

        // V chunks 0-7 issued now; latency hides under mask+softmax
        f16x8 vfa[8];
#pragma unroll
        for (int c = 0; c < 8; c++) vfa[c] = vload(t, c);

        if (t >= nt64 - 2) {  // only the two diagonal-adjacent tiles mask
#pragma unroll
          for (int ni = 0; ni < 4; ni++) {
            int kvg = kv0 + ni * 16 + lg * 4;
#pragma unroll
            for (int r4 = 0; r4 < 4; r4++)
              if (kvg + r4 > qrow) sf[ni][r4] = -1e30f;
          }
        }
        // online softmax (log2 domain), lane-local + 2 shfl (max only)
        float pm = fmaxf(fmaxf(fmaxf(sf[0][0], sf[0][1]), fmaxf(sf[0][2], sf[0][3])),
                         fmaxf(fmaxf(sf[1][0], sf[1][1]), fmaxf(sf[1][2], sf[1][3])));
        pm = fmaxf(pm, fmaxf(fmaxf(fmaxf(sf[2][0], sf[2][1]), fmaxf(sf[2][2], sf[2][3])),
                             fmaxf(fmaxf(sf[3][0], sf[3][1]), fmaxf(sf[3][2], sf[3][3]))));
        pm = fmaxf(pm, __shfl_xor(pm, 16));
        pm = fmaxf(pm, __shfl_xor(pm, 32));
        // T13 defer-max: keep old m while tile max hasn't outgrown it by >8
        float scl = 1.f;
        bool defer = __all(pm <= m + 8.f);
        if (!defer) {
          float mn = fmaxf(m, pm);
          scl = __builtin_amdgcn_exp2f(m - mn);
          m = mn;
        }
        float rsum = 0.f;
#pragma unroll
        for (int ni = 0; ni < 4; ni++)
#pragma unroll
          for (int r4 = 0; r4 < 4; r4++) {
            float pv = __builtin_amdgcn_exp2f(sf[ni][r4] - m);
            sf[ni][r4] = pv;
            rsum += pv;
          }
        lsum = lsum * scl + rsum;  // lane-local; cross-lane in epilogue

        // rescale O^T (skipped on defer tiles)
        if (!defer) {
#pragma unroll
          for (int nj = 0; nj < 8; nj++)
#pragma unroll
            for (int r4 = 0; r4 < 4; r4++) oacc[nj][r4] *= scl;
        }

        // ZERO-SHUFFLE pack: pa[kk] = [sf[2kk][0..3], sf[2kk+1][0..3]]
        f16x8 pa[2];
#pragma unroll
        for (int kk = 0; kk < 2; kk++) {
          i32x4 wv;
          wv.x = cvt_pk_i32(sf[2 * kk][0], sf[2 * kk][1]);
          wv.y = cvt_pk_i32(sf[2 * kk][2], sf[2 * kk][3]);
          wv.z = cvt_pk_i32(sf[2 * kk + 1][0], sf[2 * kk + 1][1]);
          wv.w = cvt_pk_i32(sf[2 * kk + 1][2], sf[2 * kk + 1][3]);
          pa[kk] = __builtin_bit_cast(f16x8, wv);
        }

        __builtin_amdgcn_s_setprio(1);
        // PV first half: nj 0-3 from pre-issued vfa (chunk = nj*2+kk)
#pragma unroll
        for (int kk = 0; kk < 2; kk++)
#pragma unroll
          for (int nj = 0; nj < 4; nj++)
            oacc[nj] = __builtin_amdgcn_mfma_f32_16x16x32_f16(vfa[nj * 2 + kk], pa[kk], oacc[nj], 0, 0, 0);
        // PV second half: nj 4-7, in-loop batches of 4
#pragma unroll
        for (int njb = 0; njb < 2; njb++) {
          f16x8 vf[4];
#pragma unroll
          for (int jj = 0; jj < 2; jj++)
#pragma unroll
            for (int kk = 0; kk < 2; kk++)
              vf[jj * 2 + kk] = vload(t, (4 + njb * 2 + jj) * 2 + kk);
#pragma unroll
          for (int kk = 0; kk < 2; kk++)
#pragma unroll
            for (int jj = 0; jj < 2; jj++)
              oacc[4 + njb * 2 + jj] = __builtin_amdgcn_mfma_f32_16x16x32_f16(
                  vf[jj * 2 + kk], pa[kk], oacc[4 + njb * 2 + jj], 0, 0, 0);
        }
        __builtin_amdgcn_s_setprio(0);
      }
    }

    // per-pass epilogue: quad-reduce lane-local lsum; write O into the Q
    // columns of qkv (this block's own rows, already consumed).
    lsum += __shfl_xor(lsum, 16);
    lsum += __shfl_xor(lsum, 32);
    float inv = 1.f / lsum;
#pragma unroll
    for (int nj = 0; nj < 8; nj++) {
      f16x4v ov;
#pragma unroll
      for (int r4 = 0; r4 < 4; r4++) ov[r4] = (f16)(oacc[nj][r4] * inv);
      *(f16x4v*)(qp + nj * 16 + lg * 4) = ov;
    }
  }
}

extern "C" void kernel_launch(void* const* d_in, const int* in_sizes, int n_in,
                              void* d_out, int out_size, void* d_ws, size_t ws_size,
                              hipStream_t stream) {
  (void)in_sizes; (void)n_in; (void)out_size; (void)ws_size;
  const float* x = (const float*)d_in[0];
  // d_in[1] = mask (causal, reproduced analytically)
  const float* Wq = (const float*)d_in[2];
  const float* Wk = (const float*)d_in[3];
  const float* Wv = (const float*)d_in[4];
  const float* Wo = (const float*)d_in[5];
  const int* stp = (const int*)d_in[6];
  float* out = (float*)d_out;

  const size_t MS = (size_t)B_ * S_;  // 8192
  f16* xh = (f16*)d_ws;                         // 32MB
  f16* wqt = xh + MS * D_;                      // wqt|wkt|wvt|wot contiguous, 32MB
  f16* wot = wqt + (size_t)3 * D_ * D_;
  f16* qkv = wot + (size_t)D_ * D_;             // 8192 x 6144 f16, ~100MB
  float2* tab = (float2*)(qkv + MS * (size_t)QKV_ST);

  cvt_f32_to_f16<<<16384, 256, 0, stream>>>(x, xh, (long)(MS * D_));
  wtrans4<<<dim3(4096, 4), 256, 0, stream>>>(Wq, Wk, Wv, Wo, wqt);
  // ONE 768-block launch = 3 subgroup GEMMs (Q,K,V) sharing A in L2;
  // V subgroup writes V^T fragment-linear (vtrans2 fused away).
  gemm8<f16><<<768, 512, 0, stream>>>(xh, wqt, qkv, 8192, 2048, 2048, 2048, QKV_ST,
                                      (long)D_ * D_, 2048);
  rope_table<<<512, 256, 0, stream>>>(tab, stp);
  // K roped in place (qkv cols 2048-4095); Q-RoPE fused into attn.
  rope_apply_k<<<4096, 256, 0, stream>>>(qkv, tab, (long)(MS * 1024));
  // attn reads Q/K/V^T from qkv, writes O into qkv's Q columns
  attn<<<512, 512, 0, stream>>>(qkv, tab);
  // Wo GEMM: A = qkv Q-columns (lda=6144)
  gemm8<float><<<256, 512, 0, stream>>>(qkv, wot, out, 8192, 2048, 2048, QKV_ST, 2048, 0, 0);
}

// Round 18
// 425.375 us; speedup vs baseline: 1.0529x; 1.0529x over previous
//
#include <hip/hip_runtime.h>
#include <hip/hip_fp16.h>

typedef _Float16 f16;
typedef __attribute__((ext_vector_type(2))) _Float16 f16x2;
typedef __attribute__((ext_vector_type(4))) _Float16 f16x4v;
typedef __attribute__((ext_vector_type(8))) _Float16 f16x8;
typedef __attribute__((ext_vector_type(4))) float f32x4;
typedef __attribute__((ext_vector_type(4))) int i32x4;

#define DEV __device__ __forceinline__

static constexpr int S_ = 2048;
static constexpr int D_ = 2048;
static constexpr int H_ = 16;
static constexpr int HD_ = 128;
static constexpr int B_ = 4;
static constexpr int QKV_ST = 6144;  // fused qkv row stride (Q|K|V)

typedef const __attribute__((address_space(1))) void* gptr_t;
typedef __attribute__((address_space(3))) void* lptr_t;

// async global->LDS, 16B per lane. LDS dest must be wave-uniform; HW writes
// dest + lane*16 (m104 semantics). Compiler manages m0.
DEV void gl_lds16(const void* gsrc, void* lds) {
  __builtin_amdgcn_global_load_lds((gptr_t)gsrc, (lptr_t)lds, 16, 0, 0);
}

// f32 pair -> packed f16x2 bits (v_cvt_pkrtz_f16_f32)
DEV int cvt_pk_i32(float a, float b) {
  return __builtin_bit_cast(int, __builtin_amdgcn_cvt_pkrtz(a, b));
}

__global__ __launch_bounds__(256) void cvt_f32_to_f16(const float* __restrict__ in,
                                                      f16* __restrict__ out, long n) {
  long i0 = ((long)blockIdx.x * 256 + threadIdx.x) * 4;
  long stride = (long)gridDim.x * 256 * 4;
  for (long i = i0; i < n; i += stride) {
    float4 v = *(const float4*)(in + i);
    f16x4v o;
    o[0] = (f16)v.x; o[1] = (f16)v.y; o[2] = (f16)v.z; o[3] = (f16)v.w;
    *(f16x4v*)(out + i) = o;
  }
}

// W (2048 x 2048, row-major K x N) -> Wt (N x K) fp16; 4 weights, one launch.
__global__ __launch_bounds__(256) void wtrans4(const float* __restrict__ W0, const float* __restrict__ W1,
                                               const float* __restrict__ W2, const float* __restrict__ W3,
                                               f16* __restrict__ Wt) {
  __shared__ float tile[32][33];
  int wi = blockIdx.y;
  const float* W = wi == 0 ? W0 : wi == 1 ? W1 : wi == 2 ? W2 : W3;
  f16* dst = Wt + (size_t)wi * D_ * D_;
  int bx = blockIdx.x & 63, by = blockIdx.x >> 6;
  int r0 = by << 5, c0 = bx << 5;
  int tx = threadIdx.x & 31, ty = threadIdx.x >> 5;
#pragma unroll
  for (int i = 0; i < 4; i++) {
    int r = ty + i * 8;
    tile[r][tx] = W[(size_t)(r0 + r) * D_ + c0 + tx];
  }
  __syncthreads();
#pragma unroll
  for (int i = 0; i < 4; i++) {
    int r = ty + i * 8;
    dst[(size_t)(c0 + r) * D_ + r0 + tx] = (f16)tile[tx][r];
  }
}

// swizzled LDS fragment read: [128][64] f16 half-tile, full 3-bit XOR
// swizzle (R14: conflicts measured 0): group = (s*4+lg)^(ln&7).
DEV f16x8 lds_frag(const f16* half, int row, int s, int lg) {
  int byte = row * 128 + s * 64 + lg * 16;
  byte ^= (row & 7) << 4;
  return *(const f16x8*)((const char*)half + byte);
}

// C = A(MxK, row stride lda) * Bt(NxK)^T ; C row stride ldc. 256x256 tile,
// BK=64, 8 waves, 512 thr. Multi-subgroup fusion: subgroup = bid/nwg picks
// B/C offsets (QKV GEMMs share A in one grid). ONE-BARRIER K-loop (R15/16).
// STAGE ORDER (R17 lesson): ds_reads FIRST, stages AFTER -- issuing stages
// before the fragment reads put the returning staged data (~200cy L2) on
// the LDS port exactly during the ds_read window (MfmaUtil 43.7->36,
// 215->249us). R15/16 order restored.
// V-SUBGROUP EPILOGUE (kept from R17): wi==2 writes V^T directly in the
// fragment-linear sigma layout attn consumes (deletes vtrans2). Lane
// mapping matches sigma exactly; each thread's 4 r4-values form one
// contiguous 8B f16x4 (coalesced 512B/wave). VT2 linear space L is
// EMBEDDED in the V columns of qkv: f16 addr = (L>>11)*ldc + (L&2047).
template <typename CT>
__global__ __launch_bounds__(512, 2) void gemm8(const f16* __restrict__ A, const f16* __restrict__ Bt,
                                                CT* __restrict__ C, int M, int N, int K,
                                                int lda, int ldc, long subB, long subC) {
  __shared__ alignas(16) f16 As[2][2][128 * 64];
  __shared__ alignas(16) f16 Bs[2][2][128 * 64];
  int nbx = N >> 8;
  int nwg = (M >> 8) * nbx;  // per-subgroup wg count (%8==0; ours: 256)
  int bid = blockIdx.x;
  int wi = bid / nwg;                            // subgroup (0 if plain)
  int bidl = bid - wi * nwg;
  Bt += (size_t)wi * subB;
  C += (size_t)wi * subC;
  int wg = (bidl & 7) * (nwg >> 3) + (bidl >> 3);  // XCD-contiguous chunks
  int bx = wg % nbx, by = wg / nbx;
  int tid = threadIdx.x, w = tid >> 6, l = tid & 63;
  int wm = w >> 2, wn = w & 3, lg = l >> 4, ln = l & 15;
  int nt = K >> 6;
  const f16* Ab = A + (size_t)(by * 256) * lda;
  const f16* Bb = Bt + (size_t)(bx * 256) * K;

  // stage one [128][64] half-tile: linear LDS dest (gl_lds16 requirement),
  // source slot = (l&7) ^ (row&7) -- same involution as lds_frag (rule #21).
  auto stageA = [&](const f16* src0, int kt, f16* dst) {
#pragma unroll
    for (int j = 0; j < 2; j++) {
      int c = j * 8 + w;                       // 1KB chunk
      int row = c * 8 + (l >> 3);
      int scol = ((l & 7) ^ (row & 7)) << 3;   // elems (16B units)
      gl_lds16(src0 + (size_t)row * lda + kt * 64 + scol, (char*)dst + c * 1024);
    }
  };
  auto stageB = [&](const f16* src0, int kt, f16* dst) {
#pragma unroll
    for (int j = 0; j < 2; j++) {
      int c = j * 8 + w;                       // 1KB chunk
      int row = c * 8 + (l >> 3);
      int scol = ((l & 7) ^ (row & 7)) << 3;
      gl_lds16(src0 + (size_t)row * K + kt * 64 + scol, (char*)dst + c * 1024);
    }
  };

  f32x4 acc[8][4] = {};

  // prologue: tile0 A+B
  stageA(Ab, 0, As[0][0]);
  stageA(Ab + (size_t)128 * lda, 0, As[0][1]);
  stageB(Bb, 0, Bs[0][0]);
  stageB(Bb + (size_t)128 * K, 0, Bs[0][1]);

  for (int t = 0; t < nt; t++) {
    // tile-entry drain: A(t)+B(t) landed for every wave, collective barrier
    asm volatile("s_waitcnt vmcnt(0)" ::: "memory");
    __builtin_amdgcn_s_barrier();
    asm volatile("" ::: "memory");
    const f16* Ah = As[t & 1][wm];
    const f16* Bh = Bs[t & 1][wn >> 1];
    int br0 = (wn & 1) * 64;
    f16x8 alo[4], ahi[4], b0[4], b1[4];
    // all B fragments (k0,k1) + A k0 (both row-halves)
#pragma unroll
    for (int i = 0; i < 4; i++) b0[i] = lds_frag(Bh, br0 + i * 16 + ln, 0, lg);
#pragma unroll
    for (int i = 0; i < 4; i++) b1[i] = lds_frag(Bh, br0 + i * 16 + ln, 1, lg);
#pragma unroll
    for (int i = 0; i < 4; i++) alo[i] = lds_frag(Ah, i * 16 + ln, 0, lg);
#pragma unroll
    for (int i = 0; i < 4; i++) ahi[i] = lds_frag(Ah, 64 + i * 16 + ln, 0, lg);
    // 1-ahead stage of BOTH operands into the opposite buffers
    if (t + 1 < nt) {
      stageA(Ab, t + 1, As[(t + 1) & 1][0]);
      stageA(Ab + (size_t)128 * lda, t + 1, As[(t + 1) & 1][1]);
      stageB(Bb, t + 1, Bs[(t + 1) & 1][0]);
      stageB(Bb + (size_t)128 * K, t + 1, Bs[(t + 1) & 1][1]);
    }
    __builtin_amdgcn_s_setprio(1);
#pragma unroll
    for (int mi = 0; mi < 4; mi++)
#pragma unroll
      for (int ni = 0; ni < 4; ni++) {
        acc[mi][ni] = __builtin_amdgcn_mfma_f32_16x16x32_f16(alo[mi], b0[ni], acc[mi][ni], 0, 0, 0);
        acc[mi + 4][ni] = __builtin_amdgcn_mfma_f32_16x16x32_f16(ahi[mi], b0[ni], acc[mi + 4][ni], 0, 0, 0);
      }
    __builtin_amdgcn_s_setprio(0);
    // A k1 fragments from As[t&1]: not overwritten this tile, no barrier
#pragma unroll
    for (int i = 0; i < 4; i++) alo[i] = lds_frag(Ah, i * 16 + ln, 1, lg);
#pragma unroll
    for (int i = 0; i < 4; i++) ahi[i] = lds_frag(Ah, 64 + i * 16 + ln, 1, lg);
    __builtin_amdgcn_s_setprio(1);
#pragma unroll
    for (int mi = 0; mi < 4; mi++)
#pragma unroll
      for (int ni = 0; ni < 4; ni++) {
        acc[mi][ni] = __builtin_amdgcn_mfma_f32_16x16x32_f16(alo[mi], b1[ni], acc[mi][ni], 0, 0, 0);
        acc[mi + 4][ni] = __builtin_amdgcn_mfma_f32_16x16x32_f16(ahi[mi], b1[ni], acc[mi + 4][ni], 0, 0, 0);
      }
    __builtin_amdgcn_s_setprio(0);
    asm volatile("" ::: "memory");
  }

  int row0 = by * 256 + wm * 128;
  int col0 = bx * 256 + wn * 64;
  if constexpr (sizeof(CT) == 2) {
    if (wi == 2) {
      // V^T fragment-linear write (vtrans2 fused away). Lane-local, no shfl.
#pragma unroll
      for (int mi = 0; mi < 8; mi++)
#pragma unroll
        for (int ni = 0; ni < 4; ni++) {
          f16x4v pv;
#pragma unroll
          for (int r4 = 0; r4 < 4; r4++) pv[r4] = (f16)acc[mi][ni][r4];
          int row = row0 + mi * 16 + lg * 4;
          int col = col0 + ni * 16 + ln;
          int bh = ((row >> 11) << 4) + ((col >> 7) & 15);
          int tt = (row & 2047) >> 6;
          int cc = (((col & 127) >> 4) << 1) + ((mi >> 1) & 1);
          long L = ((long)(bh * 32 + tt) << 13) + cc * 512 + l * 8 + 4 * (mi & 1);
          *(f16x4v*)(&C[(size_t)(L >> 11) * ldc + (L & 2047)]) = pv;
        }
      return;
    }
  }
#pragma unroll
  for (int mi = 0; mi < 8; mi++)
#pragma unroll
    for (int ni = 0; ni < 4; ni++)
#pragma unroll
      for (int r4 = 0; r4 < 4; r4++) {
        int row = row0 + mi * 16 + lg * 4 + r4;
        int col = col0 + ni * 16 + ln;
        float o = acc[mi][ni][r4];
        if constexpr (sizeof(CT) == 2) {
          float oo = __shfl_xor(o, 1);
          if (!(ln & 1)) {
            f16x2 pp; pp[0] = (f16)o; pp[1] = (f16)oo;
            *(f16x2*)(&C[(size_t)row * ldc + col]) = pp;
          }
        } else {
          C[(size_t)row * ldc + col] = o;
        }
      }
}

__global__ __launch_bounds__(256) void rope_table(float2* __restrict__ tab, const int* __restrict__ st) {
  int i = blockIdx.x * 256 + threadIdx.x;  // S*64 entries
  int s = i >> 6, j = i & 63;
  float theta = powf(10000.f, -(float)j / 64.f);
  float ang = (float)(s + st[0]) * theta;
  tab[i] = make_float2(cosf(ang), sinf(ang));
}

// RoPE over the K columns (2048..4095) of the fused qkv buffer, in place.
__global__ __launch_bounds__(256) void rope_apply_k(f16* __restrict__ QKV, const float2* __restrict__ tab,
                                                    long npairs) {
  long i0 = (long)blockIdx.x * 256 + threadIdx.x;
  long stride = (long)gridDim.x * 256;
  for (long p = i0; p < npairs; p += stride) {
    long row = p >> 10;            // 1024 K-pairs per row
    int jp = (int)(p & 1023);
    int s = (int)(row & (S_ - 1));
    float2 cs = tab[s * 64 + (jp & 63)];
    f16* px = QKV + row * QKV_ST + 2048 + 2 * jp;
    f16x2 v = *(const f16x2*)px;
    float xe = (float)v[0], xo = (float)v[1];
    float re = xe * cs.x - xo * cs.y;
    float ro = xe * cs.y + xo * cs.x;
    f16x2 o; o[0] = (f16)re; o[1] = (f16)ro;
    *(f16x2*)px = o;
  }
}

// flash attention, causal. 8 waves x 16 q-rows (QBLK=128), KV tile = 64,
// TWO KV-TILES PER BARRIER PERIOD: kls[2][2][64*128] (64KB, 2 blocks/CU).
// R11 config (best measured attn, 127.4us). SWAPPED QK^T; lane-local
// softmax; ZERO-SHUFFLE PV: the V GEMM epilogue wrote V^T fragment-linear
// into the V columns of qkv (linear space L -> row L>>11, col 4096+L&2047),
// so each PV A-fragment is one contiguous 1KB wave load.
// Q-RoPE fused into Q load; V chunks 0-7 after QK^T; UNIFORM blocks via
// causal pairing (15-u, u). O written back into Q columns.
// lsum quad-reduce deferred to epilogue. log2 scores; T13 defer-max THR=8.
__global__ __launch_bounds__(512, 4) void attn(f16* __restrict__ QKV, const float2* __restrict__ tab) {
  __shared__ alignas(16) f16 kls[2][2][64 * 128];
  int id = blockIdx.x;                   // 512 blocks
  int r8 = id & 7, j = id >> 3;          // j: 0..63 per XCD-residue
  int u = j & 7, g = j >> 3;             // u: pair id, g: bh group 0..7
  int bh = r8 + (g << 3);                // 8 bh's per XCD residue, bh-major
  int b = bh >> 4, h = bh & 15;
  int tid = threadIdx.x, w = tid >> 6, l = tid & 63, lg = l >> 4, ln = l & 15;

  const float QSCALE = 0.12751744910173355f;  // log2(e)/sqrt(128)
  const f16* kp = QKV + (size_t)(b * S_) * QKV_ST + 2048 + h * HD_;
  const f16* vb = QKV + 4096;
  int vrow0 = bh * 128;                  // V^T linear rows (2048 f16 each)

  auto stageK = [&](int buf, int half, int kv0) {
#pragma unroll
    for (int jj = 0; jj < 2; jj++) {
      int i = jj * 8 + w;
      int byte = i * 1024 + 16 * l;
      int r = byte >> 8;                       // row 0..63
      int c = (((byte >> 4) & 15) - r) & 15;   // inverse additive swizzle
      gl_lds16(kp + (size_t)(kv0 + r) * QKV_ST + c * 8, (char*)kls[buf][half] + i * 1024);
    }
  };
  auto vload = [&](int t, int c) -> f16x8 {
    return *(const f16x8*)(vb + (size_t)(vrow0 + t * 4 + (c >> 2)) * QKV_ST + (c & 3) * 512 + l * 8);
  };

#pragma unroll 1
  for (int pi = 0; pi < 2; pi++) {
    int qsel = pi ? u : 15 - u;          // heavy pass first (K range in L2)
    int q0 = qsel << 7;
    int qrow = q0 + w * 16 + ln;         // this lane's q row (output column)
    f16* qp = QKV + (size_t)(b * S_ + qrow) * QKV_ST + h * HD_;
    const float2* tq = tab + (size_t)qrow * 64;
    f16x8 qf[4];
#pragma unroll
    for (int kc = 0; kc < 4; kc++) {
      f16x8 q = *(const f16x8*)(qp + kc * 32 + lg * 8);
#pragma unroll
      for (int p = 0; p < 4; p++) {
        float2 cs = tq[kc * 16 + lg * 4 + p];
        float e0 = (float)q[2 * p], e1 = (float)q[2 * p + 1];
        q[2 * p] = (f16)((e0 * cs.x - e1 * cs.y) * QSCALE);
        q[2 * p + 1] = (f16)((e0 * cs.y + e1 * cs.x) * QSCALE);
      }
      qf[kc] = q;
    }

    float m = -1e30f, lsum = 0.f;        // lsum: LANE-LOCAL partial
    f32x4 oacc[8] = {};                  // O^T[d = nj*16 + lg*4 + r4][q = ln]

    int np = qsel + 1;                   // periods; nt64 = 2*qsel+2 tiles
    int nt64 = 2 * qsel + 2;
    if (pi) __syncthreads();             // kls readers from prev pass done
    stageK(0, 0, 0);                     // prologue: period 0 (tiles 0,1)
    stageK(0, 1, 64);
#pragma unroll 1
    for (int p = 0; p < np; p++) {
      __syncthreads();  // drains period-p staging; all waves done with buf
      if (p + 1 < np) {
        stageK((p + 1) & 1, 0, (2 * p + 2) << 6);
        stageK((p + 1) & 1, 1, (2 * p + 3) << 6);
      }
#pragma unroll 1
      for (int ii = 0; ii < 2; ii++) {
        int t = 2 * p + ii;
        int kv0 = t << 6;
        // wave-uniform skip: this wave's rows all precede the tile
        if (kv0 > q0 + w * 16 + 15) continue;
        const f16* kb = kls[p & 1][ii];

        // S^T = K Q^T: sf[ni][r4] = S[kv = kv0 + ni*16 + lg*4 + r4][q = ln]
        f32x4 sf[4];
        __builtin_amdgcn_s_setprio(1);
#pragma unroll
        for (int ni = 0; ni < 4; ni++) {
          int n = ni * 16 + ln;
          f32x4 s = {0.f, 0.f, 0.f, 0.f};
#pragma unroll
          for (int kc = 0; kc < 4; kc++) {
            int mch = kc * 4 + lg;
            f16x8 kf = *(const f16x8*)(&kb[n * 128 + (((mch + n) & 15) << 3)]);
            s = __builtin_amdgcn_mfma_f32_16x16x32_f16(kf, qf[kc], s, 0, 0, 0);
          }
          sf[ni] = s;
        }
        __builtin_amdgcn_s_setprio(0);

        // V chunks 0-7 issued now; latency hides under mask+softmax
        f16x8 vfa[8];
#pragma unroll
        for (int c = 0; c < 8; c++) vfa[c] = vload(t, c);

        if (t >= nt64 - 2) {  // only the two diagonal-adjacent tiles mask
#pragma unroll
          for (int ni = 0; ni < 4; ni++) {
            int kvg = kv0 + ni * 16 + lg * 4;
#pragma unroll
            for (int r4 = 0; r4 < 4; r4++)
              if (kvg + r4 > qrow) sf[ni][r4] = -1e30f;
          }
        }
        // online softmax (log2 domain), lane-local + 2 shfl (max only)
        float pm = fmaxf(fmaxf(fmaxf(sf[0][0], sf[0][1]), fmaxf(sf[0][2], sf[0][3])),
                         fmaxf(fmaxf(sf[1][0], sf[1][1]), fmaxf(sf[1][2], sf[1][3])));
        pm = fmaxf(pm, fmaxf(fmaxf(fmaxf(sf[2][0], sf[2][1]), fmaxf(sf[2][2], sf[2][3])),
                             fmaxf(fmaxf(sf[3][0], sf[3][1]), fmaxf(sf[3][2], sf[3][3]))));
        pm = fmaxf(pm, __shfl_xor(pm, 16));
        pm = fmaxf(pm, __shfl_xor(pm, 32));
        // T13 defer-max: keep old m while tile max hasn't outgrown it by >8
        float scl = 1.f;
        bool defer = __all(pm <= m + 8.f);
        if (!defer) {
          float mn = fmaxf(m, pm);
          scl = __builtin_amdgcn_exp2f(m - mn);
          m = mn;
        }
        float rsum = 0.f;
#pragma unroll
        for (int ni = 0; ni < 4; ni++)
#pragma unroll
          for (int r4 = 0; r4 < 4; r4++) {
            float pv = __builtin_amdgcn_exp2f(sf[ni][r4] - m);
            sf[ni][r4] = pv;
            rsum += pv;
          }
        lsum = lsum * scl + rsum;  // lane-local; cross-lane in epilogue

        // rescale O^T (skipped on defer tiles)
        if (!defer) {
#pragma unroll
          for (int nj = 0; nj < 8; nj++)
#pragma unroll
            for (int r4 = 0; r4 < 4; r4++) oacc[nj][r4] *= scl;
        }

        // ZERO-SHUFFLE pack: pa[kk] = [sf[2kk][0..3], sf[2kk+1][0..3]]
        f16x8 pa[2];
#pragma unroll
        for (int kk = 0; kk < 2; kk++) {
          i32x4 wv;
          wv.x = cvt_pk_i32(sf[2 * kk][0], sf[2 * kk][1]);
          wv.y = cvt_pk_i32(sf[2 * kk][2], sf[2 * kk][3]);
          wv.z = cvt_pk_i32(sf[2 * kk + 1][0], sf[2 * kk + 1][1]);
          wv.w = cvt_pk_i32(sf[2 * kk + 1][2], sf[2 * kk + 1][3]);
          pa[kk] = __builtin_bit_cast(f16x8, wv);
        }

        __builtin_amdgcn_s_setprio(1);
        // PV first half: nj 0-3 from pre-issued vfa (chunk = nj*2+kk)
#pragma unroll
        for (int kk = 0; kk < 2; kk++)
#pragma unroll
          for (int nj = 0; nj < 4; nj++)
            oacc[nj] = __builtin_amdgcn_mfma_f32_16x16x32_f16(vfa[nj * 2 + kk], pa[kk], oacc[nj], 0, 0, 0);
        // PV second half: nj 4-7, in-loop batches of 4
#pragma unroll
        for (int njb = 0; njb < 2; njb++) {
          f16x8 vf[4];
#pragma unroll
          for (int jj = 0; jj < 2; jj++)
#pragma unroll
            for (int kk = 0; kk < 2; kk++)
              vf[jj * 2 + kk] = vload(t, (4 + njb * 2 + jj) * 2 + kk);
#pragma unroll
          for (int kk = 0; kk < 2; kk++)
#pragma unroll
            for (int jj = 0; jj < 2; jj++)
              oacc[4 + njb * 2 + jj] = __builtin_amdgcn_mfma_f32_16x16x32_f16(
                  vf[jj * 2 + kk], pa[kk], oacc[4 + njb * 2 + jj], 0, 0, 0);
        }
        __builtin_amdgcn_s_setprio(0);
      }
    }

    // per-pass epilogue: quad-reduce lane-local lsum; write O into the Q
    // columns of qkv (this block's own rows, already consumed).
    lsum += __shfl_xor(lsum, 16);
    lsum += __shfl_xor(lsum, 32);
    float inv = 1.f / lsum;
#pragma unroll
    for (int nj = 0; nj < 8; nj++) {
      f16x4v ov;
#pragma unroll
      for (int r4 = 0; r4 < 4; r4++) ov[r4] = (f16)(oacc[nj][r4] * inv);
      *(f16x4v*)(qp + nj * 16 + lg * 4) = ov;
    }
  }
}

extern "C" void kernel_launch(void* const* d_in, const int* in_sizes, int n_in,
                              void* d_out, int out_size, void* d_ws, size_t ws_size,
                              hipStream_t stream) {
  (void)in_sizes; (void)n_in; (void)out_size; (void)ws_size;
  const float* x = (const float*)d_in[0];
  // d_in[1] = mask (causal, reproduced analytically)
  const float* Wq = (const float*)d_in[2];
  const float* Wk = (const float*)d_in[3];
  const float* Wv = (const float*)d_in[4];
  const float* Wo = (const float*)d_in[5];
  const int* stp = (const int*)d_in[6];
  float* out = (float*)d_out;

  const size_t MS = (size_t)B_ * S_;  // 8192
  f16* xh = (f16*)d_ws;                         // 32MB
  f16* wqt = xh + MS * D_;                      // wqt|wkt|wvt|wot contiguous, 32MB
  f16* wot = wqt + (size_t)3 * D_ * D_;
  f16* qkv = wot + (size_t)D_ * D_;             // 8192 x 6144 f16, ~100MB
  float2* tab = (float2*)(qkv + MS * (size_t)QKV_ST);

  cvt_f32_to_f16<<<16384, 256, 0, stream>>>(x, xh, (long)(MS * D_));
  wtrans4<<<dim3(4096, 4), 256, 0, stream>>>(Wq, Wk, Wv, Wo, wqt);
  // ONE 768-block launch = 3 subgroup GEMMs (Q,K,V) sharing A in L2;
  // V subgroup writes V^T fragment-linear (vtrans2 fused away).
  gemm8<f16><<<768, 512, 0, stream>>>(xh, wqt, qkv, 8192, 2048, 2048, 2048, QKV_ST,
                                      (long)D_ * D_, 2048);
  rope_table<<<512, 256, 0, stream>>>(tab, stp);
  // K roped in place (qkv cols 2048-4095); Q-RoPE fused into attn.
  rope_apply_k<<<4096, 256, 0, stream>>>(qkv, tab, (long)(MS * 1024));
  // attn reads Q/K/V^T from qkv, writes O into qkv's Q columns
  attn<<<512, 512, 0, stream>>>(qkv, tab);
  // Wo GEMM: A = qkv Q-columns (lda=6144)
  gemm8<float><<<256, 512, 0, stream>>>(qkv, wot, out, 8192, 2048, 2048, QKV_ST, 2048, 0, 0);
}

// Round 19
// 423.376 us; speedup vs baseline: 1.0579x; 1.0047x over previous
//
#include <hip/hip_runtime.h>
#include <hip/hip_fp16.h>

typedef _Float16 f16;
typedef __attribute__((ext_vector_type(2))) _Float16 f16x2;
typedef __attribute__((ext_vector_type(4))) _Float16 f16x4v;
typedef __attribute__((ext_vector_type(8))) _Float16 f16x8;
typedef __attribute__((ext_vector_type(4))) float f32x4;
typedef __attribute__((ext_vector_type(4))) int i32x4;

#define DEV __device__ __forceinline__

static constexpr int S_ = 2048;
static constexpr int D_ = 2048;
static constexpr int H_ = 16;
static constexpr int HD_ = 128;
static constexpr int B_ = 4;
static constexpr int QKV_ST = 6144;  // fused qkv row stride (Q|K|V)

typedef const __attribute__((address_space(1))) void* gptr_t;
typedef __attribute__((address_space(3))) void* lptr_t;

// async global->LDS, 16B per lane. LDS dest must be wave-uniform; HW writes
// dest + lane*16 (m104 semantics). Compiler manages m0.
DEV void gl_lds16(const void* gsrc, void* lds) {
  __builtin_amdgcn_global_load_lds((gptr_t)gsrc, (lptr_t)lds, 16, 0, 0);
}

// f32 pair -> packed f16x2 bits (v_cvt_pkrtz_f16_f32)
DEV int cvt_pk_i32(float a, float b) {
  return __builtin_bit_cast(int, __builtin_amdgcn_cvt_pkrtz(a, b));
}

__global__ __launch_bounds__(256) void cvt_f32_to_f16(const float* __restrict__ in,
                                                      f16* __restrict__ out, long n) {
  long i0 = ((long)blockIdx.x * 256 + threadIdx.x) * 4;
  long stride = (long)gridDim.x * 256 * 4;
  for (long i = i0; i < n; i += stride) {
    float4 v = *(const float4*)(in + i);
    f16x4v o;
    o[0] = (f16)v.x; o[1] = (f16)v.y; o[2] = (f16)v.z; o[3] = (f16)v.w;
    *(f16x4v*)(out + i) = o;
  }
}

// W (2048 x 2048, row-major K x N) -> Wt (N x K) fp16; 4 weights, one launch.
__global__ __launch_bounds__(256) void wtrans4(const float* __restrict__ W0, const float* __restrict__ W1,
                                               const float* __restrict__ W2, const float* __restrict__ W3,
                                               f16* __restrict__ Wt) {
  __shared__ float tile[32][33];
  int wi = blockIdx.y;
  const float* W = wi == 0 ? W0 : wi == 1 ? W1 : wi == 2 ? W2 : W3;
  f16* dst = Wt + (size_t)wi * D_ * D_;
  int bx = blockIdx.x & 63, by = blockIdx.x >> 6;
  int r0 = by << 5, c0 = bx << 5;
  int tx = threadIdx.x & 31, ty = threadIdx.x >> 5;
#pragma unroll
  for (int i = 0; i < 4; i++) {
    int r = ty + i * 8;
    tile[r][tx] = W[(size_t)(r0 + r) * D_ + c0 + tx];
  }
  __syncthreads();
#pragma unroll
  for (int i = 0; i < 4; i++) {
    int r = ty + i * 8;
    dst[(size_t)(c0 + r) * D_ + r0 + tx] = (f16)tile[tx][r];
  }
}

// swizzled LDS fragment read: [128][64] f16 half-tile, full 3-bit XOR
// swizzle (R14: conflicts measured 0): group = (s*4+lg)^(ln&7).
DEV f16x8 lds_frag(const f16* half, int row, int s, int lg) {
  int byte = row * 128 + s * 64 + lg * 16;
  byte ^= (row & 7) << 4;
  return *(const f16x8*)((const char*)half + byte);
}

// C = A(MxK, row stride lda) * Bt(NxK)^T ; C row stride ldc. 256x256 tile,
// BK=64, 8 waves, 512 thr. Multi-subgroup fusion: subgroup = bid/nwg picks
// B/C offsets (QKV GEMMs share A in one grid). ONE-BARRIER K-loop (R15/16).
// STAGE ORDER (R17 lesson): ds_reads FIRST, stages AFTER -- issuing stages
// before the fragment reads put the returning staged data on the LDS port
// during the ds_read window (MfmaUtil 43.7->36). R18 confirmed recovery.
// V-SUBGROUP EPILOGUE: wi==2 writes V^T directly in the fragment-linear
// sigma layout attn consumes (deletes vtrans2); each thread's 4 r4-values
// form one contiguous 8B f16x4 (coalesced 512B/wave). VT2 linear space L
// EMBEDDED in V columns of qkv: f16 addr = (L>>11)*ldc + (L&2047).
template <typename CT>
__global__ __launch_bounds__(512, 2) void gemm8(const f16* __restrict__ A, const f16* __restrict__ Bt,
                                                CT* __restrict__ C, int M, int N, int K,
                                                int lda, int ldc, long subB, long subC) {
  __shared__ alignas(16) f16 As[2][2][128 * 64];
  __shared__ alignas(16) f16 Bs[2][2][128 * 64];
  int nbx = N >> 8;
  int nwg = (M >> 8) * nbx;  // per-subgroup wg count (%8==0; ours: 256)
  int bid = blockIdx.x;
  int wi = bid / nwg;                            // subgroup (0 if plain)
  int bidl = bid - wi * nwg;
  Bt += (size_t)wi * subB;
  C += (size_t)wi * subC;
  int wg = (bidl & 7) * (nwg >> 3) + (bidl >> 3);  // XCD-contiguous chunks
  int bx = wg % nbx, by = wg / nbx;
  int tid = threadIdx.x, w = tid >> 6, l = tid & 63;
  int wm = w >> 2, wn = w & 3, lg = l >> 4, ln = l & 15;
  int nt = K >> 6;
  const f16* Ab = A + (size_t)(by * 256) * lda;
  const f16* Bb = Bt + (size_t)(bx * 256) * K;

  // stage one [128][64] half-tile: linear LDS dest (gl_lds16 requirement),
  // source slot = (l&7) ^ (row&7) -- same involution as lds_frag (rule #21).
  auto stageA = [&](const f16* src0, int kt, f16* dst) {
#pragma unroll
    for (int j = 0; j < 2; j++) {
      int c = j * 8 + w;                       // 1KB chunk
      int row = c * 8 + (l >> 3);
      int scol = ((l & 7) ^ (row & 7)) << 3;   // elems (16B units)
      gl_lds16(src0 + (size_t)row * lda + kt * 64 + scol, (char*)dst + c * 1024);
    }
  };
  auto stageB = [&](const f16* src0, int kt, f16* dst) {
#pragma unroll
    for (int j = 0; j < 2; j++) {
      int c = j * 8 + w;                       // 1KB chunk
      int row = c * 8 + (l >> 3);
      int scol = ((l & 7) ^ (row & 7)) << 3;
      gl_lds16(src0 + (size_t)row * K + kt * 64 + scol, (char*)dst + c * 1024);
    }
  };

  f32x4 acc[8][4] = {};

  // prologue: tile0 A+B
  stageA(Ab, 0, As[0][0]);
  stageA(Ab + (size_t)128 * lda, 0, As[0][1]);
  stageB(Bb, 0, Bs[0][0]);
  stageB(Bb + (size_t)128 * K, 0, Bs[0][1]);

  for (int t = 0; t < nt; t++) {
    // tile-entry drain: A(t)+B(t) landed for every wave, collective barrier
    asm volatile("s_waitcnt vmcnt(0)" ::: "memory");
    __builtin_amdgcn_s_barrier();
    asm volatile("" ::: "memory");
    const f16* Ah = As[t & 1][wm];
    const f16* Bh = Bs[t & 1][wn >> 1];
    int br0 = (wn & 1) * 64;
    f16x8 alo[4], ahi[4], b0[4], b1[4];
    // all B fragments (k0,k1) + A k0 (both row-halves)
#pragma unroll
    for (int i = 0; i < 4; i++) b0[i] = lds_frag(Bh, br0 + i * 16 + ln, 0, lg);
#pragma unroll
    for (int i = 0; i < 4; i++) b1[i] = lds_frag(Bh, br0 + i * 16 + ln, 1, lg);
#pragma unroll
    for (int i = 0; i < 4; i++) alo[i] = lds_frag(Ah, i * 16 + ln, 0, lg);
#pragma unroll
    for (int i = 0; i < 4; i++) ahi[i] = lds_frag(Ah, 64 + i * 16 + ln, 0, lg);
    // 1-ahead stage of BOTH operands into the opposite buffers
    if (t + 1 < nt) {
      stageA(Ab, t + 1, As[(t + 1) & 1][0]);
      stageA(Ab + (size_t)128 * lda, t + 1, As[(t + 1) & 1][1]);
      stageB(Bb, t + 1, Bs[(t + 1) & 1][0]);
      stageB(Bb + (size_t)128 * K, t + 1, Bs[(t + 1) & 1][1]);
    }
    __builtin_amdgcn_s_setprio(1);
#pragma unroll
    for (int mi = 0; mi < 4; mi++)
#pragma unroll
      for (int ni = 0; ni < 4; ni++) {
        acc[mi][ni] = __builtin_amdgcn_mfma_f32_16x16x32_f16(alo[mi], b0[ni], acc[mi][ni], 0, 0, 0);
        acc[mi + 4][ni] = __builtin_amdgcn_mfma_f32_16x16x32_f16(ahi[mi], b0[ni], acc[mi + 4][ni], 0, 0, 0);
      }
    __builtin_amdgcn_s_setprio(0);
    // A k1 fragments from As[t&1]: not overwritten this tile, no barrier
#pragma unroll
    for (int i = 0; i < 4; i++) alo[i] = lds_frag(Ah, i * 16 + ln, 1, lg);
#pragma unroll
    for (int i = 0; i < 4; i++) ahi[i] = lds_frag(Ah, 64 + i * 16 + ln, 1, lg);
    __builtin_amdgcn_s_setprio(1);
#pragma unroll
    for (int mi = 0; mi < 4; mi++)
#pragma unroll
      for (int ni = 0; ni < 4; ni++) {
        acc[mi][ni] = __builtin_amdgcn_mfma_f32_16x16x32_f16(alo[mi], b1[ni], acc[mi][ni], 0, 0, 0);
        acc[mi + 4][ni] = __builtin_amdgcn_mfma_f32_16x16x32_f16(ahi[mi], b1[ni], acc[mi + 4][ni], 0, 0, 0);
      }
    __builtin_amdgcn_s_setprio(0);
    asm volatile("" ::: "memory");
  }

  int row0 = by * 256 + wm * 128;
  int col0 = bx * 256 + wn * 64;
  if constexpr (sizeof(CT) == 2) {
    if (wi == 2) {
      // V^T fragment-linear write (vtrans2 fused away). Lane-local, no shfl.
#pragma unroll
      for (int mi = 0; mi < 8; mi++)
#pragma unroll
        for (int ni = 0; ni < 4; ni++) {
          f16x4v pv;
#pragma unroll
          for (int r4 = 0; r4 < 4; r4++) pv[r4] = (f16)acc[mi][ni][r4];
          int row = row0 + mi * 16 + lg * 4;
          int col = col0 + ni * 16 + ln;
          int bh = ((row >> 11) << 4) + ((col >> 7) & 15);
          int tt = (row & 2047) >> 6;
          int cc = (((col & 127) >> 4) << 1) + ((mi >> 1) & 1);
          long L = ((long)(bh * 32 + tt) << 13) + cc * 512 + l * 8 + 4 * (mi & 1);
          *(f16x4v*)(&C[(size_t)(L >> 11) * ldc + (L & 2047)]) = pv;
        }
      return;
    }
  }
#pragma unroll
  for (int mi = 0; mi < 8; mi++)
#pragma unroll
    for (int ni = 0; ni < 4; ni++)
#pragma unroll
      for (int r4 = 0; r4 < 4; r4++) {
        int row = row0 + mi * 16 + lg * 4 + r4;
        int col = col0 + ni * 16 + ln;
        float o = acc[mi][ni][r4];
        if constexpr (sizeof(CT) == 2) {
          float oo = __shfl_xor(o, 1);
          if (!(ln & 1)) {
            f16x2 pp; pp[0] = (f16)o; pp[1] = (f16)oo;
            *(f16x2*)(&C[(size_t)row * ldc + col]) = pp;
          }
        } else {
          C[(size_t)row * ldc + col] = o;
        }
      }
}

__global__ __launch_bounds__(256) void rope_table(float2* __restrict__ tab, const int* __restrict__ st) {
  int i = blockIdx.x * 256 + threadIdx.x;  // S*64 entries
  int s = i >> 6, j = i & 63;
  float theta = powf(10000.f, -(float)j / 64.f);
  float ang = (float)(s + st[0]) * theta;
  tab[i] = make_float2(cosf(ang), sinf(ang));
}

// RoPE over the K columns (2048..4095) of the fused qkv buffer, in place.
// VECTORIZED (R19): 4 pairs = 16B per thread (old: 4B f16x2, half-coalesced
// 256B/wave). 4 consecutive theta indices never cross the 64-entry table
// boundary (4 | 64), so cs loads stay simple. Wave accesses = 1KB coalesced.
__global__ __launch_bounds__(256) void rope_apply_k(f16* __restrict__ QKV, const float2* __restrict__ tab,
                                                    long nquads) {
  long i0 = (long)blockIdx.x * 256 + threadIdx.x;
  long stride = (long)gridDim.x * 256;
  for (long q = i0; q < nquads; q += stride) {
    long row = q >> 8;             // 256 quads per 2048-wide row
    int jq = (int)(q & 255) * 4;   // first pair index (0..1020, step 4)
    int s = (int)(row & (S_ - 1));
    const float2* tp = tab + s * 64 + (jq & 63);
    f16* px = QKV + row * QKV_ST + 2048 + 2 * jq;
    f16x8 v = *(const f16x8*)px;
#pragma unroll
    for (int p = 0; p < 4; p++) {
      float2 cs = tp[p];
      float xe = (float)v[2 * p], xo = (float)v[2 * p + 1];
      v[2 * p] = (f16)(xe * cs.x - xo * cs.y);
      v[2 * p + 1] = (f16)(xe * cs.y + xo * cs.x);
    }
    *(f16x8*)px = v;
  }
}

// flash attention, causal. 8 waves x 16 q-rows (QBLK=128), KV tile = 64,
// TWO KV-TILES PER BARRIER PERIOD: kls[2][2][64*128] (64KB, 2 blocks/CU).
// R11 config (best measured attn, 127.4us). SWAPPED QK^T; lane-local
// softmax; ZERO-SHUFFLE PV: the V GEMM epilogue wrote V^T fragment-linear
// into the V columns of qkv (linear space L -> row L>>11, col 4096+L&2047),
// so each PV A-fragment is one contiguous 1KB wave load.
// Q-RoPE fused into Q load; V chunks 0-7 after QK^T; UNIFORM blocks via
// causal pairing (15-u, u). O written back into Q columns.
// lsum quad-reduce deferred to epilogue. log2 scores; T13 defer-max THR=8.
__global__ __launch_bounds__(512, 4) void attn(f16* __restrict__ QKV, const float2* __restrict__ tab) {
  __shared__ alignas(16) f16 kls[2][2][64 * 128];
  int id = blockIdx.x;                   // 512 blocks
  int r8 = id & 7, j = id >> 3;          // j: 0..63 per XCD-residue
  int u = j & 7, g = j >> 3;             // u: pair id, g: bh group 0..7
  int bh = r8 + (g << 3);                // 8 bh's per XCD residue, bh-major
  int b = bh >> 4, h = bh & 15;
  int tid = threadIdx.x, w = tid >> 6, l = tid & 63, lg = l >> 4, ln = l & 15;

  const float QSCALE = 0.12751744910173355f;  // log2(e)/sqrt(128)
  const f16* kp = QKV + (size_t)(b * S_) * QKV_ST + 2048 + h * HD_;
  const f16* vb = QKV + 4096;
  int vrow0 = bh * 128;                  // V^T linear rows (2048 f16 each)

  auto stageK = [&](int buf, int half, int kv0) {
#pragma unroll
    for (int jj = 0; jj < 2; jj++) {
      int i = jj * 8 + w;
      int byte = i * 1024 + 16 * l;
      int r = byte >> 8;                       // row 0..63
      int c = (((byte >> 4) & 15) - r) & 15;   // inverse additive swizzle
      gl_lds16(kp + (size_t)(kv0 + r) * QKV_ST + c * 8, (char*)kls[buf][half] + i * 1024);
    }
  };
  auto vload = [&](int t, int c) -> f16x8 {
    return *(const f16x8*)(vb + (size_t)(vrow0 + t * 4 + (c >> 2)) * QKV_ST + (c & 3) * 512 + l * 8);
  };

#pragma unroll 1
  for (int pi = 0; pi < 2; pi++) {
    int qsel = pi ? u : 15 - u;          // heavy pass first (K range in L2)
    int q0 = qsel << 7;
    int qrow = q0 + w * 16 + ln;         // this lane's q row (output column)
    f16* qp = QKV + (size_t)(b * S_ + qrow) * QKV_ST + h * HD_;
    const float2* tq = tab + (size_t)qrow * 64;
    f16x8 qf[4];
#pragma unroll
    for (int kc = 0; kc < 4; kc++) {
      f16x8 q = *(const f16x8*)(qp + kc * 32 + lg * 8);
#pragma unroll
      for (int p = 0; p < 4; p++) {
        float2 cs = tq[kc * 16 + lg * 4 + p];
        float e0 = (float)q[2 * p], e1 = (float)q[2 * p + 1];
        q[2 * p] = (f16)((e0 * cs.x - e1 * cs.y) * QSCALE);
        q[2 * p + 1] = (f16)((e0 * cs.y + e1 * cs.x) * QSCALE);
      }
      qf[kc] = q;
    }

    float m = -1e30f, lsum = 0.f;        // lsum: LANE-LOCAL partial
    f32x4 oacc[8] = {};                  // O^T[d = nj*16 + lg*4 + r4][q = ln]

    int np = qsel + 1;                   // periods; nt64 = 2*qsel+2 tiles
    int nt64 = 2 * qsel + 2;
    if (pi) __syncthreads();             // kls readers from prev pass done
    stageK(0, 0, 0);                     // prologue: period 0 (tiles 0,1)
    stageK(0, 1, 64);
#pragma unroll 1
    for (int p = 0; p < np; p++) {
      __syncthreads();  // drains period-p staging; all waves done with buf
      if (p + 1 < np) {
        stageK((p + 1) & 1, 0, (2 * p + 2) << 6);
        stageK((p + 1) & 1, 1, (2 * p + 3) << 6);
      }
#pragma unroll 1
      for (int ii = 0; ii < 2; ii++) {
        int t = 2 * p + ii;
        int kv0 = t << 6;
        // wave-uniform skip: this wave's rows all precede the tile
        if (kv0 > q0 + w * 16 + 15) continue;
        const f16* kb = kls[p & 1][ii];

        // S^T = K Q^T: sf[ni][r4] = S[kv = kv0 + ni*16 + lg*4 + r4][q = ln]
        f32x4 sf[4];
        __builtin_amdgcn_s_setprio(1);
#pragma unroll
        for (int ni = 0; ni < 4; ni++) {
          int n = ni * 16 + ln;
          f32x4 s = {0.f, 0.f, 0.f, 0.f};
#pragma unroll
          for (int kc = 0; kc < 4; kc++) {
            int mch = kc * 4 + lg;
            f16x8 kf = *(const f16x8*)(&kb[n * 128 + (((mch + n) & 15) << 3)]);
            s = __builtin_amdgcn_mfma_f32_16x16x32_f16(kf, qf[kc], s, 0, 0, 0);
          }
          sf[ni] = s;
        }
        __builtin_amdgcn_s_setprio(0);

        // V chunks 0-7 issued now; latency hides under mask+softmax
        f16x8 vfa[8];
#pragma unroll
        for (int c = 0; c < 8; c++) vfa[c] = vload(t, c);

        if (t >= nt64 - 2) {  // only the two diagonal-adjacent tiles mask
#pragma unroll
          for (int ni = 0; ni < 4; ni++) {
            int kvg = kv0 + ni * 16 + lg * 4;
#pragma unroll
            for (int r4 = 0; r4 < 4; r4++)
              if (kvg + r4 > qrow) sf[ni][r4] = -1e30f;
          }
        }
        // online softmax (log2 domain), lane-local + 2 shfl (max only)
        float pm = fmaxf(fmaxf(fmaxf(sf[0][0], sf[0][1]), fmaxf(sf[0][2], sf[0][3])),
                         fmaxf(fmaxf(sf[1][0], sf[1][1]), fmaxf(sf[1][2], sf[1][3])));
        pm = fmaxf(pm, fmaxf(fmaxf(fmaxf(sf[2][0], sf[2][1]), fmaxf(sf[2][2], sf[2][3])),
                             fmaxf(fmaxf(sf[3][0], sf[3][1]), fmaxf(sf[3][2], sf[3][3]))));
        pm = fmaxf(pm, __shfl_xor(pm, 16));
        pm = fmaxf(pm, __shfl_xor(pm, 32));
        // T13 defer-max: keep old m while tile max hasn't outgrown it by >8
        float scl = 1.f;
        bool defer = __all(pm <= m + 8.f);
        if (!defer) {
          float mn = fmaxf(m, pm);
          scl = __builtin_amdgcn_exp2f(m - mn);
          m = mn;
        }
        float rsum = 0.f;
#pragma unroll
        for (int ni = 0; ni < 4; ni++)
#pragma unroll
          for (int r4 = 0; r4 < 4; r4++) {
            float pv = __builtin_amdgcn_exp2f(sf[ni][r4] - m);
            sf[ni][r4] = pv;
            rsum += pv;
          }
        lsum = lsum * scl + rsum;  // lane-local; cross-lane in epilogue

        // rescale O^T (skipped on defer tiles)
        if (!defer) {
#pragma unroll
          for (int nj = 0; nj < 8; nj++)
#pragma unroll
            for (int r4 = 0; r4 < 4; r4++) oacc[nj][r4] *= scl;
        }

        // ZERO-SHUFFLE pack: pa[kk] = [sf[2kk][0..3], sf[2kk+1][0..3]]
        f16x8 pa[2];
#pragma unroll
        for (int kk = 0; kk < 2; kk++) {
          i32x4 wv;
          wv.x = cvt_pk_i32(sf[2 * kk][0], sf[2 * kk][1]);
          wv.y = cvt_pk_i32(sf[2 * kk][2], sf[2 * kk][3]);
          wv.z = cvt_pk_i32(sf[2 * kk + 1][0], sf[2 * kk + 1][1]);
          wv.w = cvt_pk_i32(sf[2 * kk + 1][2], sf[2 * kk + 1][3]);
          pa[kk] = __builtin_bit_cast(f16x8, wv);
        }

        __builtin_amdgcn_s_setprio(1);
        // PV first half: nj 0-3 from pre-issued vfa (chunk = nj*2+kk)
#pragma unroll
        for (int kk = 0; kk < 2; kk++)
#pragma unroll
          for (int nj = 0; nj < 4; nj++)
            oacc[nj] = __builtin_amdgcn_mfma_f32_16x16x32_f16(vfa[nj * 2 + kk], pa[kk], oacc[nj], 0, 0, 0);
        // PV second half: nj 4-7, in-loop batches of 4
#pragma unroll
        for (int njb = 0; njb < 2; njb++) {
          f16x8 vf[4];
#pragma unroll
          for (int jj = 0; jj < 2; jj++)
#pragma unroll
            for (int kk = 0; kk < 2; kk++)
              vf[jj * 2 + kk] = vload(t, (4 + njb * 2 + jj) * 2 + kk);
#pragma unroll
          for (int kk = 0; kk < 2; kk++)
#pragma unroll
            for (int jj = 0; jj < 2; jj++)
              oacc[4 + njb * 2 + jj] = __builtin_amdgcn_mfma_f32_16x16x32_f16(
                  vf[jj * 2 + kk], pa[kk], oacc[4 + njb * 2 + jj], 0, 0, 0);
        }
        __builtin_amdgcn_s_setprio(0);
      }
    }

    // per-pass epilogue: quad-reduce lane-local lsum; write O into the Q
    // columns of qkv (this block's own rows, already consumed).
    lsum += __shfl_xor(lsum, 16);
    lsum += __shfl_xor(lsum, 32);
    float inv = 1.f / lsum;
#pragma unroll
    for (int nj = 0; nj < 8; nj++) {
      f16x4v ov;
#pragma unroll
      for (int r4 = 0; r4 < 4; r4++) ov[r4] = (f16)(oacc[nj][r4] * inv);
      *(f16x4v*)(qp + nj * 16 + lg * 4) = ov;
    }
  }
}

extern "C" void kernel_launch(void* const* d_in, const int* in_sizes, int n_in,
                              void* d_out, int out_size, void* d_ws, size_t ws_size,
                              hipStream_t stream) {
  (void)in_sizes; (void)n_in; (void)out_size; (void)ws_size;
  const float* x = (const float*)d_in[0];
  // d_in[1] = mask (causal, reproduced analytically)
  const float* Wq = (const float*)d_in[2];
  const float* Wk = (const float*)d_in[3];
  const float* Wv = (const float*)d_in[4];
  const float* Wo = (const float*)d_in[5];
  const int* stp = (const int*)d_in[6];
  float* out = (float*)d_out;

  const size_t MS = (size_t)B_ * S_;  // 8192
  f16* xh = (f16*)d_ws;                         // 32MB
  f16* wqt = xh + MS * D_;                      // wqt|wkt|wvt|wot contiguous, 32MB
  f16* wot = wqt + (size_t)3 * D_ * D_;
  f16* qkv = wot + (size_t)D_ * D_;             // 8192 x 6144 f16, ~100MB
  float2* tab = (float2*)(qkv + MS * (size_t)QKV_ST);

  cvt_f32_to_f16<<<16384, 256, 0, stream>>>(x, xh, (long)(MS * D_));
  wtrans4<<<dim3(4096, 4), 256, 0, stream>>>(Wq, Wk, Wv, Wo, wqt);
  // ONE 768-block launch = 3 subgroup GEMMs (Q,K,V) sharing A in L2;
  // V subgroup writes V^T fragment-linear (vtrans2 fused away).
  gemm8<f16><<<768, 512, 0, stream>>>(xh, wqt, qkv, 8192, 2048, 2048, 2048, QKV_ST,
                                      (long)D_ * D_, 2048);
  rope_table<<<512, 256, 0, stream>>>(tab, stp);
  // K roped in place (qkv cols 2048-4095); Q-RoPE fused into attn.
  rope_apply_k<<<2048, 256, 0, stream>>>(qkv, tab, (long)(MS * 256));
  // attn reads Q/K/V^T from qkv, writes O into qkv's Q columns
  attn<<<512, 512, 0, stream>>>(qkv, tab);
  // Wo GEMM: A = qkv Q-columns (lda=6144)
  gemm8<float><<<256, 512, 0, stream>>>(qkv, wot, out, 8192, 2048, 2048, QKV_ST, 2048, 0, 0);
}